// Round 2
// baseline (585.922 us; speedup 1.0000x reference)
//
#include <hip/hip_runtime.h>
#include <hip/hip_bf16.h>
#include <math.h>

#define SS    16
#define NN    1024
#define RR    4
#define CINC  128
#define COUTC 128
#define RP1   5
#define EPSF  1e-7f

typedef __bf16 bf16x8 __attribute__((ext_vector_type(8)));
typedef __bf16 bf16x4 __attribute__((ext_vector_type(4)));
typedef float  f32x4  __attribute__((ext_vector_type(4)));

// Workspace layout:
//   Yt : bf16 [S*4][COUT][N]  (Y_c = X_s @ W_c, b-major)   16 MiB @ 0
//   Z  : f32  [S][N][COUT]    (X_s @ theta)                 8 MiB @ 16 MiB
//   xb : bf16 [S][N][CIN]     (x cast to bf16)              4 MiB @ 24 MiB
//   wT : bf16 [5][COUT][CIN]  (W_c^T, ch4 = theta^T)      160 KiB @ 28 MiB
#define YT_BYTES ((size_t)SS * RR * COUTC * NN * 2)
#define Z_BYTES  ((size_t)SS * NN * COUTC * 4)
#define XB_BYTES ((size_t)SS * NN * CINC * 2)

// ---------------------------------------------------------------------------
// Stage 0: cast x -> xb (bf16) and build wT[c][b][a] (c=4 is theta).
// grid = 1024 (x) + 128 (w) blocks, 256 thr
// ---------------------------------------------------------------------------
__global__ __launch_bounds__(256) void convert_kernel(
    const float* __restrict__ x, const float* __restrict__ weight,
    const float* __restrict__ theta, __bf16* __restrict__ xb,
    __bf16* __restrict__ wT)
{
    const int bx = blockIdx.x, t = threadIdx.x;
    if (bx < 1024) {
        const size_t e0 = ((size_t)bx * 256 + t) * 8;
        f32x4 v0 = *(const f32x4*)(x + e0);
        f32x4 v1 = *(const f32x4*)(x + e0 + 4);
        bf16x8 o;
        o[0] = (__bf16)v0.x; o[1] = (__bf16)v0.y; o[2] = (__bf16)v0.z; o[3] = (__bf16)v0.w;
        o[4] = (__bf16)v1.x; o[5] = (__bf16)v1.y; o[6] = (__bf16)v1.z; o[7] = (__bf16)v1.w;
        *(bf16x8*)(xb + e0) = o;
    } else if (t < 128) {
        const int a = bx - 1024;                      // 0..127
        f32x4 wv = *(const f32x4*)(weight + ((size_t)a * COUTC + t) * RR);
        wT[(0 * COUTC + t) * CINC + a] = (__bf16)wv.x;
        wT[(1 * COUTC + t) * CINC + a] = (__bf16)wv.y;
        wT[(2 * COUTC + t) * CINC + a] = (__bf16)wv.z;
        wT[(3 * COUTC + t) * CINC + a] = (__bf16)wv.w;
        wT[(4 * COUTC + t) * CINC + a] = (__bf16)theta[(size_t)a * COUTC + t];
    }
}

// ---------------------------------------------------------------------------
// Stage 1: Yt[(s*4+c)*128+b][j] = bf16( sum_a xb[s][j][a] * wT[c][b][a] )
//          Z[s][j][b] (ch==4).  All fragments straight from global (L2-hot):
//          no LDS, no barriers. grid = 16 jt * 5 ch * 16 s = 1280 blocks.
//          bx = (jt*5+ch)*16 + s  ->  XCD = s%8 (co-locate per-s data in L2).
// ---------------------------------------------------------------------------
__global__ __launch_bounds__(256) void prep_kernel(
    const __bf16* __restrict__ xb, const __bf16* __restrict__ wT,
    __bf16* __restrict__ Yt, float* __restrict__ Z)
{
    const int bx = blockIdx.x;
    const int s  = bx & 15;
    const int r  = bx >> 4;          // 0..79
    const int ch = r % 5;
    const int jt = r / 5;            // 0..15  (64-token tile)

    const int t = threadIdx.x, lane = t & 63, w = t >> 6;
    const int m16 = lane & 15, quad = lane >> 4;

    const __bf16* xrow = xb + ((size_t)(s * NN) + jt * 64 + w * 16 + m16) * CINC;
    const __bf16* wch  = wT + (size_t)ch * COUTC * CINC;

    f32x4 acc[8];
#pragma unroll
    for (int i = 0; i < 8; ++i) acc[i] = (f32x4){0.f, 0.f, 0.f, 0.f};

#pragma unroll
    for (int k0 = 0; k0 < CINC; k0 += 32) {
        const bf16x8 af = *(const bf16x8*)(xrow + k0 + quad * 8);
#pragma unroll
        for (int bs = 0; bs < 8; ++bs) {
            const bf16x8 bf = *(const bf16x8*)(wch + (size_t)(bs * 16 + m16) * CINC + k0 + quad * 8);
            acc[bs] = __builtin_amdgcn_mfma_f32_16x16x32_bf16(af, bf, acc[bs], 0, 0, 0);
        }
    }

    const int j0 = jt * 64 + w * 16 + quad * 4;      // token row base (C/D rows)
    if (ch < 4) {
#pragma unroll
        for (int bs = 0; bs < 8; ++bs) {
            const int b = bs * 16 + m16;
            bf16x4 v; v[0] = (__bf16)acc[bs][0]; v[1] = (__bf16)acc[bs][1];
                      v[2] = (__bf16)acc[bs][2]; v[3] = (__bf16)acc[bs][3];
            *(bf16x4*)(Yt + ((size_t)((s * 4 + ch) * COUTC + b)) * NN + j0) = v;
        }
    } else {
#pragma unroll
        for (int bs = 0; bs < 8; ++bs) {
            const int b = bs * 16 + m16;
#pragma unroll
            for (int r4 = 0; r4 < 4; ++r4)
                Z[((size_t)s * NN + j0 + r4) * COUTC + b] = acc[bs][r4];
        }
    }
}

// ---------------------------------------------------------------------------
// Main: out[s,i,b] = tanh( Z[s,i,b] + sum_c norm[s,i,c] * sum_j Ar[s,i,j,c]*Y_c[j,b] )
// grid = 32 itile * 16 s = 512 blocks; bx = itile*16 + s  ->  XCD = s%8
// (all 32 blocks of an s share one XCD's L2 for Y_s). 256 thr, 2 blocks/CU.
// Double-buffered A staging -> single barrier per k-step.
// ---------------------------------------------------------------------------
__global__ __launch_bounds__(256, 2) void main_kernel(
    const float* __restrict__ A, const __bf16* __restrict__ Yt,
    const float* __restrict__ Z, float* __restrict__ out)
{
    const int bx = blockIdx.x;
    const int s  = bx & 15;
    const int i0 = (bx >> 4) * 32;

    __shared__ __bf16 lA[2][4][32][40];   // [buf][c][i][j], stride 40 bf16 (16B-aligned rows)
    __shared__ float  lnorm[4][32];

    const int t = threadIdx.x;
    const int lane = t & 63, w = t >> 6;
    const int m16 = lane & 15, quad = lane >> 4;

    const int irow = t >> 3;              // staging row 0..31
    const int q    = t & 7;               // staging j-group (4 j's x 5ch = 20 dw)

    const float* Ap = A + ((size_t)(s * NN + i0 + irow) * NN) * RP1 + q * 20;

    float rs[4] = {0.f, 0.f, 0.f, 0.f};
    f32x4 acc[4][2][2];
#pragma unroll
    for (int c = 0; c < 4; ++c)
#pragma unroll
        for (int is = 0; is < 2; ++is)
#pragma unroll
            for (int bs = 0; bs < 2; ++bs) acc[c][is][bs] = (f32x4){0.f, 0.f, 0.f, 0.f};

    const __bf16* Ys = Yt + (size_t)s * 4 * COUTC * NN;

    // prologue A prefetch: 5 aligned dwordx4 = 4 j's x 5 channels
    f32x4 ld[5];
#pragma unroll
    for (int u = 0; u < 5; ++u) ld[u] = __builtin_nontemporal_load((const f32x4*)Ap + u);

    for (int kk = 0; kk < 32; ++kk) {
        const int p = kk & 1;

        {   // de-interleave channels, convert, stage to per-c LDS planes; fp32 row-sums
            const float v0[4] = {ld[0].x, ld[1].y, ld[2].z, ld[3].w};
            const float v1[4] = {ld[0].y, ld[1].z, ld[2].w, ld[4].x};
            const float v2[4] = {ld[0].z, ld[1].w, ld[3].x, ld[4].y};
            const float v3[4] = {ld[0].w, ld[2].x, ld[3].y, ld[4].z};
            const float* vv[4] = {v0, v1, v2, v3};
#pragma unroll
            for (int c = 0; c < 4; ++c) {
                const float* v = vv[c];
                rs[c] += v[0] + v[1] + v[2] + v[3];
                bf16x4 pk; pk[0] = (__bf16)v[0]; pk[1] = (__bf16)v[1];
                           pk[2] = (__bf16)v[2]; pk[3] = (__bf16)v[3];
                *(bf16x4*)&lA[p][c][irow][q * 4] = pk;
            }
        }
        __syncthreads();   // staged tile visible; prev buffer's readers done

        if (kk < 31) {     // next A step: issued right after the drain, a full
            Ap += 160;     // step (~2000 cyc) in flight before the next barrier
#pragma unroll
            for (int u = 0; u < 5; ++u) ld[u] = __builtin_nontemporal_load((const f32x4*)Ap + u);
        }

        // B-fragments straight from global (XCD-local L2-resident Y_s)
        bf16x8 bf[4][2];
        const __bf16* yp = Ys + kk * 32 + quad * 8;
#pragma unroll
        for (int c = 0; c < 4; ++c)
#pragma unroll
            for (int bs = 0; bs < 2; ++bs)
                bf[c][bs] = *(const bf16x8*)(yp + (size_t)(c * COUTC + w * 32 + bs * 16 + m16) * NN);

#pragma unroll
        for (int c = 0; c < 4; ++c) {
            const bf16x8 af0 = *(const bf16x8*)&lA[p][c][m16][quad * 8];
            const bf16x8 af1 = *(const bf16x8*)&lA[p][c][16 + m16][quad * 8];
            acc[c][0][0] = __builtin_amdgcn_mfma_f32_16x16x32_bf16(af0, bf[c][0], acc[c][0][0], 0, 0, 0);
            acc[c][0][1] = __builtin_amdgcn_mfma_f32_16x16x32_bf16(af0, bf[c][1], acc[c][0][1], 0, 0, 0);
            acc[c][1][0] = __builtin_amdgcn_mfma_f32_16x16x32_bf16(af1, bf[c][0], acc[c][1][0], 0, 0, 0);
            acc[c][1][1] = __builtin_amdgcn_mfma_f32_16x16x32_bf16(af1, bf[c][1], acc[c][1][1], 0, 0, 0);
        }
    }

    // row-sums -> norms (8 staging lanes per row, xor-shuffle reduce)
#pragma unroll
    for (int c = 0; c < 4; ++c) {
        float v = rs[c];
        v += __shfl_xor(v, 1);
        v += __shfl_xor(v, 2);
        v += __shfl_xor(v, 4);
        if (q == 0) lnorm[c][irow] = 1.0f / (v + EPSF);
    }
    __syncthreads();

    // epilogue: combine c's with norms, add Z, tanh, store
#pragma unroll
    for (int is = 0; is < 2; ++is) {
        f32x4 nv[4];
#pragma unroll
        for (int c = 0; c < 4; ++c) nv[c] = *(const f32x4*)&lnorm[c][is * 16 + quad * 4];
        const int row0 = i0 + is * 16 + quad * 4;
#pragma unroll
        for (int bs = 0; bs < 2; ++bs) {
            const int b = w * 32 + bs * 16 + m16;
#pragma unroll
            for (int r = 0; r < 4; ++r) {
                float v = acc[0][is][bs][r] * nv[0][r]
                        + acc[1][is][bs][r] * nv[1][r]
                        + acc[2][is][bs][r] * nv[2][r]
                        + acc[3][is][bs][r] * nv[3][r];
                const size_t idx = ((size_t)s * NN + row0 + r) * COUTC + b;
                out[idx] = tanhf(v + Z[idx]);
            }
        }
    }
}

extern "C" void kernel_launch(void* const* d_in, const int* in_sizes, int n_in,
                              void* d_out, int out_size, void* d_ws, size_t ws_size,
                              hipStream_t stream)
{
    const float* A      = (const float*)d_in[0];
    const float* x      = (const float*)d_in[1];
    const float* weight = (const float*)d_in[2];
    const float* theta  = (const float*)d_in[3];
    float* out = (float*)d_out;

    __bf16* Yt = (__bf16*)d_ws;
    float*  Z  = (float*)((char*)d_ws + YT_BYTES);
    __bf16* xb = (__bf16*)((char*)d_ws + YT_BYTES + Z_BYTES);
    __bf16* wT = (__bf16*)((char*)d_ws + YT_BYTES + Z_BYTES + XB_BYTES);

    convert_kernel<<<dim3(1024 + 128), dim3(256), 0, stream>>>(x, weight, theta, xb, wT);
    prep_kernel<<<dim3(SS * 5 * 16), dim3(256), 0, stream>>>(xb, wT, Yt, Z);
    main_kernel<<<dim3(SS * 32), dim3(256), 0, stream>>>(A, Yt, Z, out);
}